// Round 4
// baseline (239.427 us; speedup 1.0000x reference)
//
#include <hip/hip_runtime.h>
#include <math.h>

#define HH 96
#define WW 96
#define HW 9216
#define CIN 128
#define COUT 256

typedef __attribute__((ext_vector_type(8))) short short8;
typedef __attribute__((ext_vector_type(4))) float f32x4;

static __device__ __forceinline__ unsigned short f2bf(float f) {
  union { float f; unsigned u; } v; v.f = f;
  unsigned r = v.u + 0x7FFF + ((v.u >> 16) & 1);
  return (unsigned short)(r >> 16);
}
static __device__ __forceinline__ float bflo(unsigned u) {
  union { unsigned u; float f; } v; v.u = u << 16; return v.f;
}
static __device__ __forceinline__ float bfhi(unsigned u) {
  union { unsigned u; float f; } v; v.u = u & 0xffff0000u; return v.f;
}

// ---------------- prep kernels ----------------

// x NCHW fp32 -> xTb NHWC bf16
__global__ __launch_bounds__(256) void k_xtb(const float* __restrict__ x,
                                             unsigned short* __restrict__ xTb) {
  __shared__ float tile[32][129];
  int bid = blockIdx.x;             // b*288 + h*3 + wseg
  int wseg = bid % 3, h = (bid / 3) % 96, b = bid / 288;
  int t = threadIdx.x;
  int wl = t & 31, cg = t >> 5;
  const float* xp = x + ((size_t)(b * 128 + cg) * 96 + h) * 96 + wseg * 32 + wl;
#pragma unroll
  for (int i = 0; i < 16; ++i)
    tile[wl][cg + 8 * i] = xp[(size_t)8 * i * HW];
  __syncthreads();
  int cl = t & 127, wg = t >> 7;
  unsigned short* op = xTb + (((size_t)(b * 96 + h) * 96) + wseg * 32) * 128 + cl;
#pragma unroll
  for (int i = 0; i < 16; ++i)
    op[(size_t)(wg + 2 * i) * 128] = f2bf(tile[wg + 2 * i][cl]);
}

// weights: wTt[n][kk] (n<256, kk=kpos*128+c) and wAb[32][1152] (offset|mask|zero-pad)
__global__ void k_wts(unsigned short* __restrict__ wTt, unsigned short* __restrict__ wAb,
                      const float* __restrict__ wgt, const float* __restrict__ offw,
                      const float* __restrict__ modw) {
  int i = blockIdx.x * 256 + threadIdx.x;
  if (i < COUT * 1152) {
    int n = i / 1152, r = i % 1152, kpos = r / 128, c = r % 128;
    wTt[i] = f2bf(wgt[n * 1152 + c * 9 + kpos]);
  } else if (i < COUT * 1152 + 32 * 1152) {
    int j = i - COUT * 1152;
    int n = j / 1152, r = j % 1152, kpos = r / 128, c = r % 128;
    float v = 0.f;
    if (n < 18) v = offw[n * 1152 + c * 9 + kpos];
    else if (n < 27) v = modw[(n - 18) * 1152 + c * 9 + kpos];
    wAb[j] = f2bf(v);
  }
}

// ---------------- fused: offset-conv (phase 1) + deformable MFMA GEMM (phase 2) ----
// 576 blocks (XCD-swizzled) x 256 thr, M-tile 64 px.
// Phase 1: om tile [27][64] via MFMA on integer taps (N=32, wAb direct-global B).
// Phase 2: K-loop 9 taps x 2 halves, double-buffered A-LDS, 1 barrier per half,
//          gathers for h+1 issued post-sync (overlap MFMA), B frags direct-global.
__global__ __launch_bounds__(256, 2) void k_fused(const unsigned short* __restrict__ xTb,
                                                  const unsigned short* __restrict__ wTt,
                                                  const unsigned short* __restrict__ wAb,
                                                  const float* __restrict__ bias,
                                                  const float* __restrict__ offb,
                                                  const float* __restrict__ modb,
                                                  float* __restrict__ out) {
  __shared__ __align__(16) unsigned short Ab[2][64 * 72];   // 2 x 9216 B
  __shared__ float oml[27][64];                             // 6912 B

  int t = threadIdx.x;
  int l = t & 63;
  int w = t >> 6;
  int lm = l & 15, lq = l >> 4;
  int raw = blockIdx.x;
  int bid = (raw & 7) * 72 + (raw >> 3);   // XCD-contiguous M regions
  int pix0 = bid * 64;
  int b = pix0 / HW;
  int posim0 = pix0 % HW;

  int px = t & 63;
  int oct0 = t >> 6;
  int pos = pix0 + px;
  int ho = (pos % HW) / 96, wo = pos % 96;

  // ================= phase 1: offset/mask conv for 64 px =================
  {
    f32x4 acc2[2];
    acc2[0] = (f32x4){0.f, 0.f, 0.f, 0.f};
    acc2[1] = (f32x4){0.f, 0.f, 0.f, 0.f};
    uint4 r0, r1;
    bool valid;
    int ibase = b * HW;
    // prefetch half 0
    {
      int hy = ho - 1, hx = wo - 1;
      valid = ((unsigned)hy < 96u) && ((unsigned)hx < 96u);
      int hyc = min(max(hy, 0), 95), hxc = min(max(hx, 0), 95);
      const unsigned short* srow = xTb + ((size_t)(ibase + hyc * 96 + hxc)) * 128;
      r0 = *(const uint4*)(srow + oct0 * 8);
      r1 = *(const uint4*)(srow + (oct0 + 4) * 8);
    }
    for (int h = 0; h < 18; ++h) {
      int kpos = h >> 1;
      uint4 z = {0u, 0u, 0u, 0u};
      unsigned short* dst = Ab[h & 1] + px * 72;
      *(uint4*)(dst + oct0 * 8) = valid ? r0 : z;
      *(uint4*)(dst + (oct0 + 4) * 8) = valid ? r1 : z;
      __syncthreads();
      if (h < 17) {
        int h2 = h + 1, kp2 = h2 >> 1, c02 = (h2 & 1) * 64;
        int hy = ho + kp2 / 3 - 1, hx = wo + kp2 % 3 - 1;
        valid = ((unsigned)hy < 96u) && ((unsigned)hx < 96u);
        int hyc = min(max(hy, 0), 95), hxc = min(max(hx, 0), 95);
        const unsigned short* srow = xTb + ((size_t)(ibase + hyc * 96 + hxc)) * 128 + c02;
        r0 = *(const uint4*)(srow + oct0 * 8);
        r1 = *(const uint4*)(srow + (oct0 + 4) * 8);
      }
      const unsigned short* Asrc = Ab[h & 1];
      int kb = kpos * 128 + (h & 1) * 64;
#pragma unroll
      for (int ks = 0; ks < 2; ++ks) {
        short8 af = *(short8*)(Asrc + (w * 16 + lm) * 72 + ks * 32 + lq * 8);
#pragma unroll
        for (int nt = 0; nt < 2; ++nt) {
          short8 bfr = *(const short8*)(wAb + (size_t)(nt * 16 + lm) * 1152 + kb + ks * 32 + lq * 8);
          acc2[nt] = __builtin_amdgcn_mfma_f32_16x16x32_bf16(af, bfr, acc2[nt], 0, 0, 0);
        }
      }
    }
    // epilogue -> oml[n][px_local], bias + sigmoid on mask
#pragma unroll
    for (int nt = 0; nt < 2; ++nt) {
      int n = nt * 16 + lm;
      if (n < 27) {
#pragma unroll
        for (int r = 0; r < 4; ++r) {
          float v = acc2[nt][r];
          if (n < 18) v += offb[n];
          else { v += modb[n - 18]; v = 1.f / (1.f + expf(-v)); }
          oml[n][w * 16 + lq * 4 + r] = v;
        }
      }
    }
  }
  __syncthreads();

  // ================= phase 2: deformable GEMM =================
  f32x4 acc[4][4];
#pragma unroll
  for (int i = 0; i < 4; ++i)
#pragma unroll
    for (int j = 0; j < 4; ++j)
      acc[i][j] = (f32x4){0.f, 0.f, 0.f, 0.f};

  float w00, w01, w10, w11;
  int o00, o01, o10, o11;
  int ibase = b * HW;

#define GEO(KP)                                                              \
  {                                                                          \
    int kp_ = (KP);                                                          \
    float dy = oml[2 * kp_][px], dx = oml[2 * kp_ + 1][px];                  \
    float mk = oml[18 + kp_][px];                                            \
    float py = (float)(ho - 1 + kp_ / 3) + dy;                               \
    float pxf = (float)(wo - 1 + kp_ % 3) + dx;                              \
    float fy = floorf(py), fx = floorf(pxf);                                 \
    int y0 = (int)fy, x0 = (int)fx;                                          \
    float ly = py - fy, lx = pxf - fx;                                       \
    w00 = (1.f - ly) * (1.f - lx); w01 = (1.f - ly) * lx;                    \
    w10 = ly * (1.f - lx);         w11 = ly * lx;                            \
    bool vy0 = (unsigned)y0 < 96u, vy1 = (unsigned)(y0 + 1) < 96u;           \
    bool vx0 = (unsigned)x0 < 96u, vx1 = (unsigned)(x0 + 1) < 96u;           \
    w00 = (vy0 && vx0) ? w00 * mk : 0.f;                                     \
    w01 = (vy0 && vx1) ? w01 * mk : 0.f;                                     \
    w10 = (vy1 && vx0) ? w10 * mk : 0.f;                                     \
    w11 = (vy1 && vx1) ? w11 * mk : 0.f;                                     \
    int y0c = min(max(y0, 0), 95), y1c = min(max(y0 + 1, 0), 95);            \
    int x0c = min(max(x0, 0), 95), x1c = min(max(x0 + 1, 0), 95);            \
    o00 = (ibase + y0c * 96 + x0c) * 128;                                    \
    o01 = (ibase + y0c * 96 + x1c) * 128;                                    \
    o10 = (ibase + y1c * 96 + x0c) * 128;                                    \
    o11 = (ibase + y1c * 96 + x1c) * 128;                                    \
  }

  uint4 g[8];
#define GATHER(C0)                                                           \
  {                                                                          \
    int cc0 = (C0) + oct0 * 8, cc1 = (C0) + (oct0 + 4) * 8;                  \
    g[0] = *(const uint4*)(xTb + o00 + cc0);                                 \
    g[1] = *(const uint4*)(xTb + o01 + cc0);                                 \
    g[2] = *(const uint4*)(xTb + o10 + cc0);                                 \
    g[3] = *(const uint4*)(xTb + o11 + cc0);                                 \
    g[4] = *(const uint4*)(xTb + o00 + cc1);                                 \
    g[5] = *(const uint4*)(xTb + o01 + cc1);                                 \
    g[6] = *(const uint4*)(xTb + o10 + cc1);                                 \
    g[7] = *(const uint4*)(xTb + o11 + cc1);                                 \
  }

  GEO(0);
  GATHER(0);

  for (int h = 0; h < 18; ++h) {
    int kpos = h >> 1;
    // interp + write A tile
    {
      unsigned short* dst = Ab[h & 1] + px * 72;
#pragma unroll
      for (int item = 0; item < 2; ++item) {
        unsigned qa[4] = {g[4 * item].x, g[4 * item].y, g[4 * item].z, g[4 * item].w};
        unsigned qb[4] = {g[4 * item + 1].x, g[4 * item + 1].y, g[4 * item + 1].z, g[4 * item + 1].w};
        unsigned qc[4] = {g[4 * item + 2].x, g[4 * item + 2].y, g[4 * item + 2].z, g[4 * item + 2].w};
        unsigned qd[4] = {g[4 * item + 3].x, g[4 * item + 3].y, g[4 * item + 3].z, g[4 * item + 3].w};
        union { short8 v; unsigned short s[8]; } r;
#pragma unroll
        for (int j = 0; j < 4; ++j) {
          float lo = w00 * bflo(qa[j]) + w01 * bflo(qb[j]) + w10 * bflo(qc[j]) + w11 * bflo(qd[j]);
          float hi = w00 * bfhi(qa[j]) + w01 * bfhi(qb[j]) + w10 * bfhi(qc[j]) + w11 * bfhi(qd[j]);
          r.s[2 * j] = f2bf(lo);
          r.s[2 * j + 1] = f2bf(hi);
        }
        *(short8*)(dst + (oct0 + 4 * item) * 8) = r.v;
      }
    }
    __syncthreads();
    // prefetch next half (overlaps MFMA below; drained by the time of next barrier)
    if (h < 17) {
      if (h & 1) GEO(kpos + 1);
      GATHER(((h + 1) & 1) * 64);
    }
    // MFMA: A from LDS, B frags direct from global (L2-resident)
    const unsigned short* Asrc = Ab[h & 1];
    int kb = kpos * 128 + (h & 1) * 64;
#pragma unroll
    for (int ks = 0; ks < 2; ++ks) {
      short8 af[4];
#pragma unroll
      for (int mt = 0; mt < 4; ++mt)
        af[mt] = *(short8*)(Asrc + (mt * 16 + lm) * 72 + ks * 32 + lq * 8);
#pragma unroll
      for (int nt = 0; nt < 4; ++nt) {
        short8 bfr = *(const short8*)(wTt + (size_t)(w * 64 + nt * 16 + lm) * 1152 + kb + ks * 32 + lq * 8);
#pragma unroll
        for (int mt = 0; mt < 4; ++mt)
          acc[mt][nt] = __builtin_amdgcn_mfma_f32_16x16x32_bf16(af[mt], bfr, acc[mt][nt], 0, 0, 0);
      }
    }
  }
#undef GEO
#undef GATHER

  // ---- epilogue: per-wave LDS transpose -> coalesced stores
  float bias_v[4];
#pragma unroll
  for (int nt = 0; nt < 4; ++nt) bias_v[nt] = bias[w * 64 + nt * 16 + lm];
  float* ez = (float*)Ab + w * 1088;   // 64*17 floats per wave zone (reuses Ab)
#pragma unroll
  for (int nt = 0; nt < 4; ++nt) {
    __syncthreads();
#pragma unroll
    for (int mt = 0; mt < 4; ++mt)
#pragma unroll
      for (int r = 0; r < 4; ++r)
        ez[(mt * 16 + lq * 4 + r) * 17 + lm] = acc[mt][nt][r] + bias_v[nt];
    __syncthreads();
    float* ob = out + ((size_t)(b * COUT + w * 64 + nt * 16)) * HW + posim0;
#pragma unroll
    for (int j = 0; j < 16; ++j)
      ob[(size_t)j * HW + l] = ez[l * 17 + j];
  }
}

extern "C" void kernel_launch(void* const* d_in, const int* in_sizes, int n_in,
                              void* d_out, int out_size, void* d_ws, size_t ws_size,
                              hipStream_t stream) {
  const float* x      = (const float*)d_in[0];
  const float* weight = (const float*)d_in[1];
  const float* bias   = (const float*)d_in[2];
  const float* offw   = (const float*)d_in[3];
  const float* offb   = (const float*)d_in[4];
  const float* modw   = (const float*)d_in[5];
  const float* modb   = (const float*)d_in[6];
  float* out = (float*)d_out;

  unsigned short* xTb = (unsigned short*)d_ws;          // 4718592 us
  unsigned short* wTt = xTb + 4718592;                  // 294912 us
  unsigned short* wAb = wTt + 294912;                   // 36864 us
  // total ws use ~10.1 MB

  k_xtb<<<1152, 256, 0, stream>>>(x, xTb);
  k_wts<<<1296, 256, 0, stream>>>(wTt, wAb, weight, offw, modw);
  k_fused<<<576, 256, 0, stream>>>(xTb, wTt, wAb, bias, offb, modb, out);
}

// Round 5
// 219.600 us; speedup vs baseline: 1.0903x; 1.0903x over previous
//
#include <hip/hip_runtime.h>
#include <math.h>

#define HW 9216
#define CIN 128
#define COUT 256
#define RS 136   // A-tile row stride in shorts (16B-aligned, near-optimal LDS banking)

typedef __attribute__((ext_vector_type(8))) short short8;
typedef __attribute__((ext_vector_type(4))) float f32x4;

static __device__ __forceinline__ unsigned short f2bf(float f) {
  union { float f; unsigned u; } v; v.f = f;
  unsigned r = v.u + 0x7FFF + ((v.u >> 16) & 1);
  return (unsigned short)(r >> 16);
}
static __device__ __forceinline__ float bflo(unsigned u) {
  union { unsigned u; float f; } v; v.u = u << 16; return v.f;
}
static __device__ __forceinline__ float bfhi(unsigned u) {
  union { unsigned u; float f; } v; v.u = u & 0xffff0000u; return v.f;
}

// ---------------- single prep kernel ----------------
// blocks 0..1151: x NCHW fp32 -> xTb NHWC bf16
// blocks 1152..2303: wS  = main weights pre-swizzled to MFMA B-fragment order
//                    layout [tap][wave][ks][nt][lane][8]
// blocks 2304..2447: wA  = offset/mask weights swizzled, layout [tap][ks][nt2][lane][8]
__global__ __launch_bounds__(256) void k_prep(const float* __restrict__ x,
                                              unsigned short* __restrict__ xTb,
                                              unsigned short* __restrict__ wS,
                                              unsigned short* __restrict__ wA,
                                              const float* __restrict__ wgt,
                                              const float* __restrict__ offw,
                                              const float* __restrict__ modw) {
  __shared__ float tile[32][129];
  int bid = blockIdx.x;
  int t = threadIdx.x;
  if (bid < 1152) {
    int wseg = bid % 3, h = (bid / 3) % 96, b = bid / 288;
    int wl = t & 31, cg = t >> 5;
    const float* xp = x + ((size_t)(b * 128 + cg) * 96 + h) * 96 + wseg * 32 + wl;
#pragma unroll
    for (int i = 0; i < 16; ++i)
      tile[wl][cg + 8 * i] = xp[(size_t)8 * i * HW];
    __syncthreads();
    int cl = t & 127, wg = t >> 7;
    unsigned short* op = xTb + (((size_t)(b * 96 + h) * 96) + wseg * 32) * 128 + cl;
#pragma unroll
    for (int i = 0; i < 16; ++i)
      op[(size_t)(wg + 2 * i) * 128] = f2bf(tile[wg + 2 * i][cl]);
  } else if (bid < 2304) {
    int i = (bid - 1152) * 256 + t;           // < 294912
    int j = i & 7, l = (i >> 3) & 63, frag = i >> 9;
    int nt = frag & 3, ks = (frag >> 2) & 3, w = (frag >> 4) & 3, tap = frag >> 6;
    int n = w * 64 + nt * 16 + (l & 15);
    int c = ks * 32 + (l >> 4) * 8 + j;
    wS[i] = f2bf(wgt[n * 1152 + c * 9 + tap]);
  } else {
    int i = (bid - 2304) * 256 + t;           // < 36864
    int j = i & 7, l = (i >> 3) & 63, frag = i >> 9;   // frag < 72
    int nt = frag & 1, ks = (frag >> 1) & 3, tap = frag >> 3;
    int n = nt * 16 + (l & 15);
    int c = ks * 32 + (l >> 4) * 8 + j;
    float v = 0.f;
    if (n < 18) v = offw[n * 1152 + c * 9 + tap];
    else if (n < 27) v = modw[(n - 18) * 1152 + c * 9 + tap];
    wA[i] = f2bf(v);
  }
}

// ---------------- fused offset-conv + deformable MFMA GEMM ----------------
// 576 blocks (XCD-swizzled) x 256 thr. M-tile 64 px, N=256, BK=128 (full tap).
// B fragments: coalesced direct-global from pre-swizzled wS/wA (no LDS, no barrier).
// A: double-buffered LDS, 1 barrier per tap, gathers pipelined over MFMA.
__global__ __launch_bounds__(256, 2) void k_fused(const unsigned short* __restrict__ xTb,
                                                  const unsigned short* __restrict__ wS,
                                                  const unsigned short* __restrict__ wA,
                                                  const float* __restrict__ bias,
                                                  const float* __restrict__ offb,
                                                  const float* __restrict__ modb,
                                                  float* __restrict__ out) {
  __shared__ __align__(16) unsigned short Ab[2][64 * RS];   // 2 x 17408 B
  __shared__ float oml[27][64];                             // 6912 B

  int t = threadIdx.x;
  int l = t & 63, w = t >> 6;
  int lm = l & 15, lq = l >> 4;
  int raw = blockIdx.x;
  int bid = (raw & 7) * 72 + (raw >> 3);   // XCD-contiguous M regions
  int pix0 = bid * 64;
  int b = pix0 / HW;
  int posim0 = pix0 % HW;
  int ibase = b * HW;

  // ================= phase 1: offset/mask conv (N=32, integer taps) =================
  {
    int px1 = t >> 2, cq = t & 3;            // 4 threads per px, 32 c each
    int pos1 = posim0 + px1;
    int ho1 = pos1 / 96, wo1 = pos1 % 96;
    f32x4 acc2[2];
    acc2[0] = (f32x4){0.f, 0.f, 0.f, 0.f};
    acc2[1] = (f32x4){0.f, 0.f, 0.f, 0.f};
    uint4 p[4];
    bool pv;

#define LOAD1(KP)                                                             \
    {                                                                         \
      int kp_ = (KP);                                                         \
      int hy = ho1 + kp_ / 3 - 1, hx = wo1 + kp_ % 3 - 1;                     \
      pv = ((unsigned)hy < 96u) && ((unsigned)hx < 96u);                      \
      int hyc = min(max(hy, 0), 95), hxc = min(max(hx, 0), 95);               \
      const unsigned short* s = xTb + (size_t)(ibase + hyc * 96 + hxc) * 128 + cq * 32; \
      p[0] = *(const uint4*)(s);      p[1] = *(const uint4*)(s + 8);          \
      p[2] = *(const uint4*)(s + 16); p[3] = *(const uint4*)(s + 24);         \
    }
#define STORE1(BUF)                                                           \
    {                                                                         \
      unsigned short* dst = Ab[BUF] + px1 * RS + cq * 32;                     \
      uint4 z = {0u, 0u, 0u, 0u};                                             \
      *(uint4*)(dst)      = pv ? p[0] : z;  *(uint4*)(dst + 8)  = pv ? p[1] : z; \
      *(uint4*)(dst + 16) = pv ? p[2] : z;  *(uint4*)(dst + 24) = pv ? p[3] : z; \
    }

    LOAD1(0);
    STORE1(0);
    __syncthreads();
    for (int h = 0; h < 9; ++h) {
      if (h < 8) LOAD1(h + 1);               // overlaps MFMA below
      const unsigned short* Asrc = Ab[h & 1];
#pragma unroll
      for (int ks = 0; ks < 4; ++ks) {
        short8 af = *(short8*)(Asrc + (w * 16 + lm) * RS + ks * 32 + lq * 8);
#pragma unroll
        for (int nt = 0; nt < 2; ++nt) {
          short8 bfr = *(const short8*)(wA + (size_t)((((h * 4 + ks) * 2) + nt) * 64 + l) * 8);
          acc2[nt] = __builtin_amdgcn_mfma_f32_16x16x32_bf16(af, bfr, acc2[nt], 0, 0, 0);
        }
      }
      if (h < 8) STORE1((h + 1) & 1);
      __syncthreads();
    }
#undef LOAD1
#undef STORE1
    // epilogue -> oml[n][m], bias + sigmoid on mask channels
#pragma unroll
    for (int nt = 0; nt < 2; ++nt) {
      int n = nt * 16 + lm;
      if (n < 27) {
#pragma unroll
        for (int r = 0; r < 4; ++r) {
          float v = acc2[nt][r];
          if (n < 18) v += offb[n];
          else { v += modb[n - 18]; v = 1.f / (1.f + expf(-v)); }
          oml[n][w * 16 + lq * 4 + r] = v;
        }
      }
    }
  }
  __syncthreads();

  // ================= phase 2: deformable GEMM =================
  f32x4 acc[4][4];
#pragma unroll
  for (int i = 0; i < 4; ++i)
#pragma unroll
    for (int j = 0; j < 4; ++j)
      acc[i][j] = (f32x4){0.f, 0.f, 0.f, 0.f};

  int px = t & 63;
  int pos = posim0 + px;
  int ho = pos / 96, wo = pos % 96;
  float w00, w01, w10, w11;
  int o00, o01, o10, o11;
  int cb0 = w * 16, cb1 = 64 + w * 16;       // this wave's c-chunks

#define GEO(KP)                                                              \
  {                                                                          \
    int kp_ = (KP);                                                          \
    float dy = oml[2 * kp_][px], dx = oml[2 * kp_ + 1][px];                  \
    float mk = oml[18 + kp_][px];                                            \
    float py = (float)(ho - 1 + kp_ / 3) + dy;                               \
    float pxf = (float)(wo - 1 + kp_ % 3) + dx;                              \
    float fy = floorf(py), fx = floorf(pxf);                                 \
    int y0 = (int)fy, x0 = (int)fx;                                          \
    float ly = py - fy, lx = pxf - fx;                                       \
    w00 = (1.f - ly) * (1.f - lx); w01 = (1.f - ly) * lx;                    \
    w10 = ly * (1.f - lx);         w11 = ly * lx;                            \
    bool vy0 = (unsigned)y0 < 96u, vy1 = (unsigned)(y0 + 1) < 96u;           \
    bool vx0 = (unsigned)x0 < 96u, vx1 = (unsigned)(x0 + 1) < 96u;           \
    w00 = (vy0 && vx0) ? w00 * mk : 0.f;                                     \
    w01 = (vy0 && vx1) ? w01 * mk : 0.f;                                     \
    w10 = (vy1 && vx0) ? w10 * mk : 0.f;                                     \
    w11 = (vy1 && vx1) ? w11 * mk : 0.f;                                     \
    int y0c = min(max(y0, 0), 95), y1c = min(max(y0 + 1, 0), 95);            \
    int x0c = min(max(x0, 0), 95), x1c = min(max(x0 + 1, 0), 95);            \
    o00 = (ibase + y0c * 96 + x0c) * 128;                                    \
    o01 = (ibase + y0c * 96 + x1c) * 128;                                    \
    o10 = (ibase + y1c * 96 + x0c) * 128;                                    \
    o11 = (ibase + y1c * 96 + x1c) * 128;                                    \
  }

  uint4 g[8];
#define GATHER(CB)                                                           \
  {                                                                          \
    g[0] = *(const uint4*)(xTb + o00 + (CB));                                \
    g[1] = *(const uint4*)(xTb + o00 + (CB) + 8);                            \
    g[2] = *(const uint4*)(xTb + o01 + (CB));                                \
    g[3] = *(const uint4*)(xTb + o01 + (CB) + 8);                            \
    g[4] = *(const uint4*)(xTb + o10 + (CB));                                \
    g[5] = *(const uint4*)(xTb + o10 + (CB) + 8);                            \
    g[6] = *(const uint4*)(xTb + o11 + (CB));                                \
    g[7] = *(const uint4*)(xTb + o11 + (CB) + 8);                            \
  }
#define INTERP_WRITE(CB, BUF)                                                \
  {                                                                          \
    unsigned short* dst = Ab[BUF] + px * RS + (CB);                          \
    _Pragma("unroll")                                                        \
    for (int i = 0; i < 2; ++i) {                                            \
      unsigned qa[4] = {g[i].x, g[i].y, g[i].z, g[i].w};                     \
      unsigned qb[4] = {g[2 + i].x, g[2 + i].y, g[2 + i].z, g[2 + i].w};     \
      unsigned qc[4] = {g[4 + i].x, g[4 + i].y, g[4 + i].z, g[4 + i].w};     \
      unsigned qd[4] = {g[6 + i].x, g[6 + i].y, g[6 + i].z, g[6 + i].w};     \
      union { short8 v; unsigned short s[8]; } r;                            \
      _Pragma("unroll")                                                      \
      for (int j = 0; j < 4; ++j) {                                          \
        float lo = w00 * bflo(qa[j]) + w01 * bflo(qb[j]) + w10 * bflo(qc[j]) + w11 * bflo(qd[j]); \
        float hi = w00 * bfhi(qa[j]) + w01 * bfhi(qb[j]) + w10 * bfhi(qc[j]) + w11 * bfhi(qd[j]); \
        r.s[2 * j] = f2bf(lo);                                               \
        r.s[2 * j + 1] = f2bf(hi);                                           \
      }                                                                      \
      *(short8*)(dst + i * 8) = r.v;                                         \
    }                                                                        \
  }
#define MF(KS)                                                               \
  {                                                                          \
    short8 af[4];                                                            \
    _Pragma("unroll")                                                        \
    for (int mt = 0; mt < 4; ++mt)                                           \
      af[mt] = *(short8*)(Asrc + (mt * 16 + lm) * RS + (KS) * 32 + lq * 8);  \
    _Pragma("unroll")                                                        \
    for (int nt = 0; nt < 4; ++nt) {                                         \
      short8 bfr = *(const short8*)(wS + (size_t)((((h * 4 + w) * 4 + (KS)) * 4 + nt) * 64 + l) * 8); \
      _Pragma("unroll")                                                      \
      for (int mt = 0; mt < 4; ++mt)                                         \
        acc[mt][nt] = __builtin_amdgcn_mfma_f32_16x16x32_bf16(af[mt], bfr, acc[mt][nt], 0, 0, 0); \
    }                                                                        \
  }

  // preamble: stage tap 0
  GEO(0);
  GATHER(cb0);
  INTERP_WRITE(cb0, 0);
  GATHER(cb1);
  INTERP_WRITE(cb1, 0);
  __syncthreads();

  for (int h = 0; h < 9; ++h) {
    const unsigned short* Asrc = Ab[h & 1];
    if (h < 8) { GEO(h + 1); GATHER(cb0); }   // latency rides over MFMA ks=0,1
    MF(0); MF(1);
    if (h < 8) { INTERP_WRITE(cb0, (h + 1) & 1); GATHER(cb1); }
    MF(2); MF(3);
    if (h < 8) { INTERP_WRITE(cb1, (h + 1) & 1); }
    __syncthreads();
  }
#undef GEO
#undef GATHER
#undef INTERP_WRITE
#undef MF

  // ---- epilogue: per-wave LDS transpose (wave-private zones, no barriers) ----
  float bias_v[4];
#pragma unroll
  for (int nt = 0; nt < 4; ++nt) bias_v[nt] = bias[w * 64 + nt * 16 + lm];
  float* ez = (float*)Ab + w * 1088;   // 64*17 floats per wave
#pragma unroll
  for (int nt = 0; nt < 4; ++nt) {
#pragma unroll
    for (int mt = 0; mt < 4; ++mt)
#pragma unroll
      for (int r = 0; r < 4; ++r)
        ez[(mt * 16 + lq * 4 + r) * 17 + lm] = acc[mt][nt][r] + bias_v[nt];
    float* ob = out + ((size_t)(b * COUT + w * 64 + nt * 16)) * HW + posim0;
#pragma unroll
    for (int j = 0; j < 16; ++j)
      ob[(size_t)j * HW + l] = ez[l * 17 + j];
  }
}

extern "C" void kernel_launch(void* const* d_in, const int* in_sizes, int n_in,
                              void* d_out, int out_size, void* d_ws, size_t ws_size,
                              hipStream_t stream) {
  const float* x      = (const float*)d_in[0];
  const float* weight = (const float*)d_in[1];
  const float* bias   = (const float*)d_in[2];
  const float* offw   = (const float*)d_in[3];
  const float* offb   = (const float*)d_in[4];
  const float* modw   = (const float*)d_in[5];
  const float* modb   = (const float*)d_in[6];
  float* out = (float*)d_out;

  unsigned short* xTb = (unsigned short*)d_ws;          // 4718592 us
  unsigned short* wS  = xTb + 4718592;                  // 294912 us
  unsigned short* wA  = wS + 294912;                    // 36864 us
  // total ws use ~10.1 MB

  k_prep<<<2448, 256, 0, stream>>>(x, xTb, wS, wA, weight, offw, modw);
  k_fused<<<576, 256, 0, stream>>>(xTb, wS, wA, bias, offb, modb, out);
}